// Round 8
// baseline (270.311 us; speedup 1.0000x reference)
//
#include <hip/hip_runtime.h>
#include <hip/hip_bf16.h>

// ---------------------------------------------------------------------------
// SwinTransformerBlock3D, f32 I/O. Round 16: swapped-operand MFMA everywhere.
// mfma(X,Y) gives D[m=4g+r <-> X's row][n=ml <-> Y's row]; A/B frags load
// identically, so swapping transposes the OUTPUT for free: lane owns row=ml
// and 4 CONSECUTIVE cols -> all epilogues vectorize (b64/float4 instead of
// scalar b16/f32). k_pm scalar mem ops/thread ~218 -> ~48; k_qkv_ln stores
// 72 scalar -> 18 b64; attention PV output 8 scalar -> 2 b64, lred deleted.
// Fragment READS unchanged (semantics proven by the existing QK swap).
// ---------------------------------------------------------------------------

#define L_TOK 87808

typedef unsigned int uint;
typedef __attribute__((ext_vector_type(8))) short short8;
typedef __attribute__((ext_vector_type(4))) float f32x4;

__device__ __forceinline__ float bflo(uint u){ union{uint x; float f;} a; a.x = u << 16; return a.f; }
__device__ __forceinline__ float bfhi(uint u){ union{uint x; float f;} a; a.x = u & 0xffff0000u; return a.f; }
__device__ __forceinline__ float bfval(unsigned short w){ union{uint x; float f;} a; a.x = (uint)w << 16; return a.f; }
__device__ __forceinline__ unsigned short f2bfbits(float f){
  union{float f; uint u;} a; a.f = f;
  uint u = a.u;
  u += 0x7fffu + ((u >> 16) & 1u);           // round-to-nearest-even
  return (unsigned short)(u >> 16);
}
__device__ __forceinline__ unsigned short bfb(float f){
  __hip_bfloat16 h = __float2bfloat16(f);
  return *reinterpret_cast<unsigned short*>(&h);
}
__device__ __forceinline__ uint pkbf(float a, float b){
  return ((uint)bfb(b) << 16) | (uint)bfb(a);
}
__device__ __forceinline__ uint pack2(float a, float b){
  return ((uint)f2bfbits(b) << 16) | (uint)f2bfbits(a);
}
__device__ __forceinline__ uint4 pack8(const float* p){
  uint4 u;
  u.x = pack2(p[0], p[1]); u.y = pack2(p[2], p[3]);
  u.z = pack2(p[4], p[5]); u.w = pack2(p[6], p[7]);
  return u;
}
__device__ __forceinline__ uint4 pack8g(const float* gp){
  float t[8];
  *(float4*)&t[0] = *(const float4*)gp;
  *(float4*)&t[4] = *(const float4*)(gp + 4);
  return pack8(t);
}
// GELU with A&S 7.1.26 erf approx (|err| < 1.5e-7, below bf16 rounding).
__device__ __forceinline__ float gelu_f(float v){
  const float ax = fabsf(v) * 0.70710678118654752f;
  const float t  = 1.0f / (1.0f + 0.3275911f * ax);
  const float poly = t*(0.254829592f + t*(-0.284496736f + t*(1.421413741f +
                     t*(-1.453152027f + t*1.061405429f))));
  float erfv = 1.0f - poly * __expf(-ax*ax);
  erfv = copysignf(erfv, v);
  return 0.5f * v * (1.0f + erfv);
}
// window-reverse + roll(+3): window-order token row -> original token index *96
__device__ __forceinline__ uint gt_of_row(uint row){
  const uint win = row / 343u, n = row % 343u;
  const uint wh = win >> 5, ww = (win >> 2) & 7u, wd = win & 3u;
  const uint ih = n / 49u, rr = n % 49u, iw = rr / 7u, id = rr % 7u;
  uint gh = wh*7u + ih + 3u; if (gh >= 56u) gh -= 56u;
  uint gw = ww*7u + iw + 3u; if (gw >= 56u) gw -= 56u;
  uint gd = wd*7u + id + 3u; if (gd >= 28u) gd -= 28u;
  return ((gh*56u + gw)*28u + gd) * 96u;
}

// ---------------------------------------------------------------------------
// K0: transpose+convert weights: dst[n*K + k] = bf16(src[k*N + n]).
// ---------------------------------------------------------------------------
__global__ __launch_bounds__(256)
void k_tr(const float* __restrict__ src, unsigned short* __restrict__ dst,
          int K, int N)
{
  const int idx = blockIdx.x * 256 + threadIdx.x;
  if (idx < K * N) {
    const int n = idx / K, k = idx % K;
    dst[idx] = f2bfbits(src[(size_t)k * N + n]);
  }
}

// ---------------------------------------------------------------------------
// K0b: all four weight transposes in one launch (432 blocks).
// ---------------------------------------------------------------------------
__global__ __launch_bounds__(256)
void k_tr4(const float* __restrict__ qkvw, unsigned short* __restrict__ qkvwt,
           const float* __restrict__ pw,   unsigned short* __restrict__ pwt,
           const float* __restrict__ f1w,  unsigned short* __restrict__ w1t,
           const float* __restrict__ f2w,  unsigned short* __restrict__ w2t)
{
  const int b = blockIdx.x, tid = threadIdx.x;
  const float* src; unsigned short* dst; int K, N, idx;
  if (b < 108)      { src = qkvw; dst = qkvwt; K = 96;  N = 288; idx = b*256 + tid; }
  else if (b < 144) { src = pw;   dst = pwt;   K = 96;  N = 96;  idx = (b-108)*256 + tid; }
  else if (b < 288) { src = f1w;  dst = w1t;   K = 96;  N = 384; idx = (b-144)*256 + tid; }
  else              { src = f2w;  dst = w2t;   K = 384; N = 96;  idx = (b-288)*256 + tid; }
  if (idx < K * N) {
    const int n = idx / K, k = idx % K;
    dst[idx] = f2bfbits(src[(size_t)k * N + n]);
  }
}

// ---------------------------------------------------------------------------
// K-mb: combined mask+bias table MB[cls][h][q][k] bf16, 8 window classes.
// ---------------------------------------------------------------------------
__global__ __launch_bounds__(256)
void k_mb(const float* __restrict__ rpbg, unsigned short* __restrict__ MB)
{
  const int idx = blockIdx.x * 256 + threadIdx.x;     // 8*3*352*352 threads
  const int cls = idx / (3*352*352);
  const int rem = idx - cls * (3*352*352);
  const int h = rem / (352*352);
  const int rem2 = rem - h * (352*352);
  const int q = rem2 / 352;
  const int k = rem2 - q * 352;
  unsigned short v = 0xFF80;                          // -inf bf16
  if (q < 343 && k < 343) {
    const int q0 = q/49, q1 = (q%49)/7, q2 = q%7;
    const int k0 = k/49, k1 = (k%49)/7, k2 = k%7;
    const int bq = q0*169 + q1*13 + q2;
    const int bk = k0*169 + k1*13 + k2;
    float bias = rpbg[(size_t)(bq - bk + 1098)*3 + h];
    int cq = 0, ck = 0;
    if (cls & 4) { cq += ((q0 < 4) ? 1 : 2)*9; ck += ((k0 < 4) ? 1 : 2)*9; }
    if (cls & 2) { cq += ((q1 < 4) ? 1 : 2)*3; ck += ((k1 < 4) ? 1 : 2)*3; }
    if (cls & 1) { cq += (q2 < 4) ? 1 : 2;     ck += (k2 < 4) ? 1 : 2; }
    if (cq != ck) bias -= 100.0f;
    v = f2bfbits(bias);
  }
  MB[idx] = v;
}

// ---------------------------------------------------------------------------
// K1 (round 16): LDS-free fused LN1 + gather + QKV GEMM, swapped output.
// lane (g,ml): row = row0+wave*16+ml, cols nt*16+4g..+3 -> b64 stores.
// ---------------------------------------------------------------------------
__global__ __launch_bounds__(256, 3)
void k_qkv_ln(const float* __restrict__ x,
              const float* __restrict__ n1g,
              const float* __restrict__ n1b,
              const unsigned short* __restrict__ qkvwt,   // [288][96]
              const float* __restrict__ bias, size_t headStride,
              __hip_bfloat16* __restrict__ qb,
              __hip_bfloat16* __restrict__ kb,
              __hip_bfloat16* __restrict__ vb)
{
  const int tid = threadIdx.x;
  const int wave = tid >> 6, lane = tid & 63;
  const int ml = lane & 15, g = lane >> 4, g8 = g*8;
  const int row0 = blockIdx.x * 64;
  const uint myrow = (uint)(row0 + wave*16 + ml);
  const uint src = gt_of_row(myrow);

  float vv[24];
  float s = 0.f, sq = 0.f;
  #pragma unroll
  for (int kc = 0; kc < 3; ++kc) {
    float t[8];
    *(float4*)&t[0] = *(const float4*)(x + src + kc*32 + g8);
    *(float4*)&t[4] = *(const float4*)(x + src + kc*32 + g8 + 4);
    #pragma unroll
    for (int j = 0; j < 8; ++j) {
      const float v = bfval(f2bfbits(t[j]));
      vv[kc*8 + j] = v;
      s += v; sq += v*v;
    }
  }
  s  += __shfl_xor(s, 16);  s  += __shfl_xor(s, 32);
  sq += __shfl_xor(sq, 16); sq += __shfl_xor(sq, 32);
  const float mean = s * (1.0f/96.0f);
  const float rstd = rsqrtf(sq*(1.0f/96.0f) - mean*mean + 1e-5f);

  short8 afrag[3];
  #pragma unroll
  for (int kc = 0; kc < 3; ++kc) {
    float gm[8], bt[8], v[8];
    *(float4*)&gm[0] = *(const float4*)(n1g + kc*32 + g8);
    *(float4*)&gm[4] = *(const float4*)(n1g + kc*32 + g8 + 4);
    *(float4*)&bt[0] = *(const float4*)(n1b + kc*32 + g8);
    *(float4*)&bt[4] = *(const float4*)(n1b + kc*32 + g8 + 4);
    #pragma unroll
    for (int j = 0; j < 8; ++j)
      v[j] = (vv[kc*8 + j] - mean)*rstd*gm[j] + bt[j];
    uint4 u = pack8(v);
    afrag[kc] = *(short8*)&u;
  }

  // swapped GEMM: D[m=wcol][n=xrow]
  f32x4 acc[18];
  #pragma unroll
  for (int i = 0; i < 18; ++i) acc[i] = (f32x4){0.f, 0.f, 0.f, 0.f};
  #pragma unroll
  for (int kc = 0; kc < 3; ++kc) {
    #pragma unroll
    for (int nt = 0; nt < 18; ++nt) {
      const short8 b = *(const short8*)(qkvwt + (size_t)(nt*16 + ml)*96 + kc*32 + g8);
      acc[nt] = __builtin_amdgcn_mfma_f32_16x16x32_bf16(b, afrag[kc], acc[nt], 0, 0, 0);
    }
  }

  const float qscale = 0.17677669529663687f;   // 32^-0.5
  #pragma unroll
  for (int nt = 0; nt < 18; ++nt) {
    const int nbase = nt * 16;
    const int part = nbase / 96;               // 0=q 1=k 2=v
    const int rem  = nbase - part * 96;
    const int h    = rem >> 5;
    const int dbase= rem & 31;                 // 0 or 16
    __hip_bfloat16* base = (part == 0) ? qb : ((part == 1) ? kb : vb);
    __hip_bfloat16* dst = base + (size_t)h * headStride;
    const float4 bv4 = *(const float4*)(bias + nbase + 4*g);
    float v0 = acc[nt][0] + bv4.x;
    float v1 = acc[nt][1] + bv4.y;
    float v2 = acc[nt][2] + bv4.z;
    float v3 = acc[nt][3] + bv4.w;
    if (part == 0) { v0 *= qscale; v1 *= qscale; v2 *= qscale; v3 *= qscale; }
    uint2 u;
    u.x = pkbf(v0, v1); u.y = pkbf(v2, v3);
    *(uint2*)&dst[(size_t)myrow*32 + dbase + 4*g] = u;
  }
}

// ---------------------------------------------------------------------------
// K2 (round 16): swapped-QK attention; PV also swapped -> lane owns row=ml,
// d=4g+r -> b64/float4 output stores; lred LDS bounce deleted.
// ---------------------------------------------------------------------------
template<bool BF16OUT>
__global__ __launch_bounds__(256, 4)
void k_attn_v10(const __hip_bfloat16* __restrict__ qg,
                const __hip_bfloat16* __restrict__ kg,
                const __hip_bfloat16* __restrict__ vg,
                size_t headStride,
                const unsigned short* __restrict__ MB,   // [8][3][352][352]
                void* __restrict__ obp)
{
  __shared__ __align__(16) unsigned short vt[32*344 + 16];   // V^T, [d][t]
  __shared__ __align__(16) unsigned short Pc[4][16*56];      // per-wave P chunk

  const int tid = threadIdx.x;
  const int wave = tid >> 6, lane = tid & 63;
  const uint win = blockIdx.x;
  const int hh = (int)blockIdx.y;
  const int mtBase = (int)blockIdx.z * 11;
  const size_t wbase = (size_t)hh * headStride + (size_t)win * (343*32);
  const unsigned short* qw = (const unsigned short*)qg + wbase;
  const unsigned short* kw = (const unsigned short*)kg + wbase;
  const unsigned short* vw = (const unsigned short*)vg + wbase;

  const uint wh = win >> 5, ww = (win >> 2) & 7u, wd = win & 3u;
  const int cls = ((wh == 7u) ? 4 : 0) | ((ww == 7u) ? 2 : 0) | ((wd == 3u) ? 1 : 0);
  const unsigned short* MBh = MB + ((size_t)cls*3 + hh) * (352*352);

  for (int t = tid; t < 343; t += 256) {
    const uint4* src = (const uint4*)(vw + (size_t)t*32);
    #pragma unroll
    for (int c4 = 0; c4 < 4; ++c4) {
      const uint4 u = src[c4];
      const int d = c4*8;
      vt[(d+0)*344 + t] = (unsigned short)(u.x & 0xffffu);
      vt[(d+1)*344 + t] = (unsigned short)(u.x >> 16);
      vt[(d+2)*344 + t] = (unsigned short)(u.y & 0xffffu);
      vt[(d+3)*344 + t] = (unsigned short)(u.y >> 16);
      vt[(d+4)*344 + t] = (unsigned short)(u.z & 0xffffu);
      vt[(d+5)*344 + t] = (unsigned short)(u.z >> 16);
      vt[(d+6)*344 + t] = (unsigned short)(u.w & 0xffffu);
      vt[(d+7)*344 + t] = (unsigned short)(u.w >> 16);
    }
  }
  if (tid < 32) vt[tid*344 + 343] = 0;
  if (tid < 16) vt[32*344 + tid] = 0;
  __syncthreads();

  const int ml = lane & 15, g = lane >> 4, g8 = g*8;
  unsigned short* Pw = &Pc[wave][0];

  for (int mt = mtBase + wave; mt < mtBase + 11; mt += 4) {
    const int q = mt*16 + ml;                          // this lane's q row
    const short8 qf = *(const short8*)(qw + (size_t)q*32 + g8);
    const unsigned short* MBq = MBh + (size_t)q * 352;
    float l = 0.0f;
    f32x4 o0 = {0.f,0.f,0.f,0.f}, o1 = {0.f,0.f,0.f,0.f};

    for (int kc = 0; kc < 11; ++kc) {
      const short8 kf0 = *(const short8*)(kw + (size_t)(kc*32 + ml)*32 + g8);
      const short8 kf1 = *(const short8*)(kw + (size_t)(kc*32 + 16 + ml)*32 + g8);
      f32x4 s0 = __builtin_amdgcn_mfma_f32_16x16x32_bf16(kf0, qf, (f32x4){0.f,0.f,0.f,0.f}, 0, 0, 0);
      f32x4 s1 = __builtin_amdgcn_mfma_f32_16x16x32_bf16(kf1, qf, (f32x4){0.f,0.f,0.f,0.f}, 0, 0, 0);

      const ushort4 u0 = *(const ushort4*)(MBq + kc*32 + 4*g);
      const ushort4 u1 = *(const ushort4*)(MBq + kc*32 + 16 + 4*g);

      float p0 = __expf(s0[0] + bfval(u0.x));
      float p1 = __expf(s0[1] + bfval(u0.y));
      float p2 = __expf(s0[2] + bfval(u0.z));
      float p3 = __expf(s0[3] + bfval(u0.w));
      float p4 = __expf(s1[0] + bfval(u1.x));
      float p5 = __expf(s1[1] + bfval(u1.y));
      float p6 = __expf(s1[2] + bfval(u1.z));
      float p7 = __expf(s1[3] + bfval(u1.w));
      l += ((p0 + p1) + (p2 + p3)) + ((p4 + p5) + (p6 + p7));

      uint2 wlo, whi;
      wlo.x = pkbf(p0, p1); wlo.y = pkbf(p2, p3);
      whi.x = pkbf(p4, p5); whi.y = pkbf(p6, p7);
      *(uint2*)&Pw[ml*56 + 4*g]      = wlo;
      *(uint2*)&Pw[ml*56 + 16 + 4*g] = whi;

      const short8 pf  = *(const short8*)&Pw[ml*56 + g8];
      const short8 vf0 = *(const short8*)&vt[(size_t)ml*344 + kc*32 + g8];
      const short8 vf1 = *(const short8*)&vt[(size_t)(16 + ml)*344 + kc*32 + g8];
      // swapped PV: D[m=d][n=q-row]
      o0 = __builtin_amdgcn_mfma_f32_16x16x32_bf16(vf0, pf, o0, 0, 0, 0);
      o1 = __builtin_amdgcn_mfma_f32_16x16x32_bf16(vf1, pf, o1, 0, 0, 0);
    }

    l += __shfl_xor(l, 16);
    l += __shfl_xor(l, 32);
    const float inv = 1.0f / l;                        // l for q = ml (lane-local)
    const int row = mt*16 + ml;
    if (row < 343) {
      const size_t base = ((size_t)win*343 + (uint)row)*96 + hh*32;
      if (BF16OUT) {
        __hip_bfloat16* op = (__hip_bfloat16*)obp + base;
        uint2 w0, w1;
        w0.x = pkbf(o0[0]*inv, o0[1]*inv); w0.y = pkbf(o0[2]*inv, o0[3]*inv);
        w1.x = pkbf(o1[0]*inv, o1[1]*inv); w1.y = pkbf(o1[2]*inv, o1[3]*inv);
        *(uint2*)&op[4*g]      = w0;
        *(uint2*)&op[16 + 4*g] = w1;
      } else {
        float* op = (float*)obp + base;
        float4 f0 = {o0[0]*inv, o0[1]*inv, o0[2]*inv, o0[3]*inv};
        float4 f1 = {o1[0]*inv, o1[1]*inv, o1[2]*inv, o1[3]*inv};
        *(float4*)&op[4*g]      = f0;
        *(float4*)&op[16 + 4*g] = f1;
      }
    }
  }
}

// ---------------------------------------------------------------------------
// K-pm (round 16): fused proj + residual + in-register LN2 + fc1/GELU + fc2 +
// residual; ALL GEMMs swapped -> vectorized epilogues throughout.
// ---------------------------------------------------------------------------
__global__ __launch_bounds__(256, 3)
void k_pm(const __hip_bfloat16* __restrict__ obb,      // window-order o, bf16
          const unsigned short* __restrict__ pwt,      // [96][96]
          const float* __restrict__ pb,
          const float* __restrict__ xin,
          const float* __restrict__ n2g,
          const float* __restrict__ n2b,
          const unsigned short* __restrict__ w1t,      // [384][96]
          const float* __restrict__ b1,
          const unsigned short* __restrict__ w2t,      // [96][384]
          const float* __restrict__ b2,
          float* __restrict__ out)
{
  __shared__ __align__(16) unsigned short As[64][104];
  __shared__ __align__(16) unsigned short Rs[64][104];   // xres bf16 (residual)
  __shared__ __align__(16) unsigned short inter[64][200];
  __shared__ uint gtO[64];

  const int tid = threadIdx.x;
  const int wave = tid >> 6, lane = tid & 63;
  const int row0 = blockIdx.x * 64;
  const int ml = lane & 15, g = lane >> 4, g8 = g*8;

  // ---- prefetch: this lane's proj row + residual (flies under staging) ----
  const int rowl_p = wave*16 + ml;
  const uint grow = gt_of_row((uint)(row0 + rowl_p));
  float4 xv[6], pb4[6];
  #pragma unroll
  for (int nt = 0; nt < 6; ++nt) {
    xv[nt]  = *(const float4*)(xin + grow + nt*16 + 4*g);
    pb4[nt] = *(const float4*)(pb  + nt*16 + 4*g);
  }
  if (tid < 64) gtO[tid] = gt_of_row((uint)(row0 + tid));
  for (int i = tid; i < 768; i += 256) {
    const int r = i / 12, kk = (i % 12) * 8;
    *(uint4*)&As[r][kk] = *(const uint4*)(obb + (size_t)(row0 + r)*96 + kk);
  }
  __syncthreads();

  // ---- proj (swapped): D[m=pcol][n=row] ----
  f32x4 acc[6];
  #pragma unroll
  for (int i = 0; i < 6; ++i) acc[i] = (f32x4){0.f, 0.f, 0.f, 0.f};
  #pragma unroll
  for (int kc = 0; kc < 3; ++kc) {
    const short8 a = *(const short8*)&As[wave*16 + ml][kc*32 + g8];
    #pragma unroll
    for (int nt = 0; nt < 6; ++nt) {
      const short8 b = *(const short8*)(pwt + (size_t)(nt*16 + ml)*96 + kc*32 + g8);
      acc[nt] = __builtin_amdgcn_mfma_f32_16x16x32_bf16(b, a, acc[nt], 0, 0, 0);
    }
  }

  // prefetch w1t H0 fragments (consumed after next barrier)
  short8 bf[3][3];
  #pragma unroll
  for (int nt = 0; nt < 3; ++nt)
    #pragma unroll
    for (int kc = 0; kc < 3; ++kc)
      bf[nt][kc] = *(const short8*)(w1t + (size_t)(48*wave + 16*nt + ml)*96 + kc*32 + g8);

  // ---- epilogue + in-register LN2 (one row per lane) ----
  float vr[6][4];
  float s = 0.f, sq = 0.f;
  #pragma unroll
  for (int nt = 0; nt < 6; ++nt) {
    const float v0 = acc[nt][0] + pb4[nt].x + xv[nt].x;
    const float v1 = acc[nt][1] + pb4[nt].y + xv[nt].y;
    const float v2 = acc[nt][2] + pb4[nt].z + xv[nt].z;
    const float v3 = acc[nt][3] + pb4[nt].w + xv[nt].w;
    const unsigned short us0 = bfb(v0), us1 = bfb(v1), us2 = bfb(v2), us3 = bfb(v3);
    uint2 u; u.x = (uint)us0 | ((uint)us1 << 16); u.y = (uint)us2 | ((uint)us3 << 16);
    *(uint2*)&Rs[rowl_p][nt*16 + 4*g] = u;
    vr[nt][0] = bfval(us0); vr[nt][1] = bfval(us1);
    vr[nt][2] = bfval(us2); vr[nt][3] = bfval(us3);
    s  += (vr[nt][0] + vr[nt][1]) + (vr[nt][2] + vr[nt][3]);
    sq += (vr[nt][0]*vr[nt][0] + vr[nt][1]*vr[nt][1]) +
          (vr[nt][2]*vr[nt][2] + vr[nt][3]*vr[nt][3]);
  }
  s  += __shfl_xor(s, 16);  s  += __shfl_xor(s, 32);
  sq += __shfl_xor(sq, 16); sq += __shfl_xor(sq, 32);
  const float mean = s * (1.0f/96.0f);
  const float rstd = rsqrtf(sq*(1.0f/96.0f) - mean*mean + 1e-5f);
  #pragma unroll
  for (int nt = 0; nt < 6; ++nt) {
    const float4 gv4 = *(const float4*)(n2g + nt*16 + 4*g);
    const float4 bt4 = *(const float4*)(n2b + nt*16 + 4*g);
    uint2 u;
    u.x = pkbf((vr[nt][0]-mean)*rstd*gv4.x + bt4.x,
               (vr[nt][1]-mean)*rstd*gv4.y + bt4.y);
    u.y = pkbf((vr[nt][2]-mean)*rstd*gv4.z + bt4.z,
               (vr[nt][3]-mean)*rstd*gv4.w + bt4.w);
    *(uint2*)&As[rowl_p][nt*16 + 4*g] = u;
  }
  __syncthreads();

  // ---- fc1/fc2 (swapped), two 192-col halves, acc2 persistent ----
  short8 af[4][3];
  #pragma unroll
  for (int mt = 0; mt < 4; ++mt)
    #pragma unroll
    for (int kc = 0; kc < 3; ++kc)
      af[mt][kc] = *(const short8*)&As[mt*16 + ml][kc*32 + g8];

  const int rb = 32 * (wave >> 1);
  const int cb = 48 * (wave & 1);
  f32x4 acc2[2][3];
  #pragma unroll
  for (int i = 0; i < 2; ++i)
    #pragma unroll
    for (int nt = 0; nt < 3; ++nt)
      acc2[i][nt] = (f32x4){0.f, 0.f, 0.f, 0.f};

  short8 bf1[3][3];

  // ===== H0: fc1 (swapped: D[m=col][n=row]) =====
  {
    f32x4 a1[4][3];
    #pragma unroll
    for (int mt = 0; mt < 4; ++mt)
      #pragma unroll
      for (int nt = 0; nt < 3; ++nt)
        a1[mt][nt] = (f32x4){0.f, 0.f, 0.f, 0.f};
    #pragma unroll
    for (int kc = 0; kc < 3; ++kc)
      #pragma unroll
      for (int nt = 0; nt < 3; ++nt)
        #pragma unroll
        for (int mt = 0; mt < 4; ++mt)
          a1[mt][nt] = __builtin_amdgcn_mfma_f32_16x16x32_bf16(bf[nt][kc], af[mt][kc], a1[mt][nt], 0, 0, 0);

    // prefetch w1t H1 fragments (consumed after 2 barriers)
    #pragma unroll
    for (int nt = 0; nt < 3; ++nt)
      #pragma unroll
      for (int kc = 0; kc < 3; ++kc)
        bf1[nt][kc] = *(const short8*)(w1t + (size_t)(192 + 48*wave + 16*nt + ml)*96 + kc*32 + g8);

    #pragma unroll
    for (int nt = 0; nt < 3; ++nt) {
      const float4 b14 = *(const float4*)(b1 + 48*wave + 16*nt + 4*g);
      const int c = 48*wave + 16*nt + 4*g;
      #pragma unroll
      for (int mt = 0; mt < 4; ++mt) {
        const float w0 = gelu_f(a1[mt][nt][0] + b14.x);
        const float w1 = gelu_f(a1[mt][nt][1] + b14.y);
        const float w2 = gelu_f(a1[mt][nt][2] + b14.z);
        const float w3 = gelu_f(a1[mt][nt][3] + b14.w);
        uint2 u; u.x = pkbf(w0, w1); u.y = pkbf(w2, w3);
        *(uint2*)&inter[mt*16 + ml][c] = u;
      }
    }
  }
  __syncthreads();

  // ===== H0: fc2 partial (swapped) =====
  #pragma unroll
  for (int kcl = 0; kcl < 6; ++kcl) {
    const short8 a0 = *(const short8*)&inter[rb + ml][kcl*32 + g8];
    const short8 a1i = *(const short8*)&inter[rb + 16 + ml][kcl*32 + g8];
    #pragma unroll
    for (int nt = 0; nt < 3; ++nt) {
      const short8 b = *(const short8*)(w2t + (size_t)(cb + 16*nt + ml)*384 + kcl*32 + g8);
      acc2[0][nt] = __builtin_amdgcn_mfma_f32_16x16x32_bf16(b, a0, acc2[0][nt], 0, 0, 0);
      acc2[1][nt] = __builtin_amdgcn_mfma_f32_16x16x32_bf16(b, a1i, acc2[1][nt], 0, 0, 0);
    }
  }
  __syncthreads();                       // inter reuse

  // ===== H1: fc1 =====
  {
    f32x4 a1[4][3];
    #pragma unroll
    for (int mt = 0; mt < 4; ++mt)
      #pragma unroll
      for (int nt = 0; nt < 3; ++nt)
        a1[mt][nt] = (f32x4){0.f, 0.f, 0.f, 0.f};
    #pragma unroll
    for (int kc = 0; kc < 3; ++kc)
      #pragma unroll
      for (int nt = 0; nt < 3; ++nt)
        #pragma unroll
        for (int mt = 0; mt < 4; ++mt)
          a1[mt][nt] = __builtin_amdgcn_mfma_f32_16x16x32_bf16(bf1[nt][kc], af[mt][kc], a1[mt][nt], 0, 0, 0);

    #pragma unroll
    for (int nt = 0; nt < 3; ++nt) {
      const float4 b14 = *(const float4*)(b1 + 192 + 48*wave + 16*nt + 4*g);
      const int c = 48*wave + 16*nt + 4*g;
      #pragma unroll
      for (int mt = 0; mt < 4; ++mt) {
        const float w0 = gelu_f(a1[mt][nt][0] + b14.x);
        const float w1 = gelu_f(a1[mt][nt][1] + b14.y);
        const float w2 = gelu_f(a1[mt][nt][2] + b14.z);
        const float w3 = gelu_f(a1[mt][nt][3] + b14.w);
        uint2 u; u.x = pkbf(w0, w1); u.y = pkbf(w2, w3);
        *(uint2*)&inter[mt*16 + ml][c] = u;
      }
    }
  }
  __syncthreads();

  // ===== H1: fc2 partial + epilogue =====
  #pragma unroll
  for (int kcl = 0; kcl < 6; ++kcl) {
    const short8 a0 = *(const short8*)&inter[rb + ml][kcl*32 + g8];
    const short8 a1i = *(const short8*)&inter[rb + 16 + ml][kcl*32 + g8];
    #pragma unroll
    for (int nt = 0; nt < 3; ++nt) {
      const short8 b = *(const short8*)(w2t + (size_t)(cb + 16*nt + ml)*384 + 192 + kcl*32 + g8);
      acc2[0][nt] = __builtin_amdgcn_mfma_f32_16x16x32_bf16(b, a0, acc2[0][nt], 0, 0, 0);
      acc2[1][nt] = __builtin_amdgcn_mfma_f32_16x16x32_bf16(b, a1i, acc2[1][nt], 0, 0, 0);
    }
  }

  #pragma unroll
  for (int i = 0; i < 2; ++i) {
    const int rowl = rb + 16*i + ml;
    const size_t go = (size_t)gtO[rowl];
    #pragma unroll
    for (int nt = 0; nt < 3; ++nt) {
      const int c = cb + 16*nt + 4*g;
      const float4 b24 = *(const float4*)(b2 + c);
      const uint2 ru = *(const uint2*)&Rs[rowl][c];
      float4 o;
      o.x = acc2[i][nt][0] + b24.x + bflo(ru.x);
      o.y = acc2[i][nt][1] + b24.y + bfhi(ru.x);
      o.z = acc2[i][nt][2] + b24.z + bflo(ru.y);
      o.w = acc2[i][nt][3] + b24.w + bfhi(ru.y);
      *(float4*)(out + go + c) = o;
    }
  }
}

// ---------------------------------------------------------------------------
// Fallback kernels (round-12 proven): k_proj + k_mlp, used when ws can't host
// the bf16 obb buffer.
// ---------------------------------------------------------------------------
__global__ __launch_bounds__(256)
void k_proj(const float* __restrict__ A,
            const unsigned short* __restrict__ pwt,      // [96][96]
            const float* __restrict__ bias,
            const float* __restrict__ xin,
            __hip_bfloat16* __restrict__ xres)
{
  __shared__ __align__(16) unsigned short As[128][104];
  const int tid = threadIdx.x;
  const int wave = tid >> 6, lane = tid & 63;
  const int row0 = blockIdx.x * 128;

  for (int i = tid; i < 1536; i += 256) {
    const int r = i / 12, kk = (i % 12) * 8;
    *(uint4*)&As[r][kk] = pack8g(A + (size_t)(row0 + r)*96 + kk);
  }
  __syncthreads();

  f32x4 acc[2][6];
  #pragma unroll
  for (int mt = 0; mt < 2; ++mt)
    #pragma unroll
    for (int i = 0; i < 6; ++i) acc[mt][i] = (f32x4){0.f, 0.f, 0.f, 0.f};
  const int ml = lane & 15, q8 = (lane >> 4) * 8;
  #pragma unroll
  for (int kc = 0; kc < 3; ++kc) {
    const short8 a0 = *(const short8*)&As[wave*32 + ml][kc*32 + q8];
    const short8 a1 = *(const short8*)&As[wave*32 + 16 + ml][kc*32 + q8];
    #pragma unroll
    for (int nt = 0; nt < 6; ++nt) {
      const short8 b = *(const short8*)(pwt + (size_t)(nt*16 + ml)*96 + kc*32 + q8);
      acc[0][nt] = __builtin_amdgcn_mfma_f32_16x16x32_bf16(a0, b, acc[0][nt], 0, 0, 0);
      acc[1][nt] = __builtin_amdgcn_mfma_f32_16x16x32_bf16(a1, b, acc[1][nt], 0, 0, 0);
    }
  }

  #pragma unroll
  for (int mt = 0; mt < 2; ++mt) {
    #pragma unroll
    for (int r = 0; r < 4; ++r) {
      const uint row = (uint)(row0 + wave*32 + mt*16 + (lane >> 4)*4 + r);
      const size_t gt = (size_t)gt_of_row(row);
      #pragma unroll
      for (int nt = 0; nt < 6; ++nt) {
        const int col = nt*16 + ml;
        xres[gt + col] = __float2bfloat16(acc[mt][nt][r] + bias[col] + xin[gt + col]);
      }
    }
  }
}

__global__ __launch_bounds__(256, 4)
void k_mlp(const __hip_bfloat16* __restrict__ xresb,
           const float* __restrict__ n2g,
           const float* __restrict__ n2b,
           const unsigned short* __restrict__ w1t,       // [384][96]
           const float* __restrict__ b1,
           const unsigned short* __restrict__ w2t,       // [96][384]
           const float* __restrict__ b2,
           float* __restrict__ out)
{
  __shared__ __align__(16) unsigned short As[64][104];
  __shared__ __align__(16) unsigned short inter[64][200];
  float* scr  = (float*)&inter[0][0];
  float* pSum = scr;
  float* pSq  = scr + 256;
  float* gL   = scr + 512;
  float* bL   = scr + 608;
  float* mL   = scr + 704;
  float* sL   = scr + 768;

  const int tid = threadIdx.x;
  const int wave = tid >> 6, lane = tid & 63;
  const int row0 = blockIdx.x * 64;
  const int ml = lane & 15, g = lane >> 4, g8 = g*8;

  if (tid < 96) { gL[tid] = n2g[tid]; bL[tid] = n2b[tid]; }
  for (int i = tid; i < 768; i += 256) {
    const int r = i / 12, kk = (i % 12) * 8;
    *(uint4*)&As[r][kk] = *(const uint4*)(xresb + (size_t)(row0 + r)*96 + kk);
  }
  __syncthreads();

  {
    const int r = tid & 63, seg = tid >> 6;
    float s = 0.0f, sq = 0.0f;
    #pragma unroll
    for (int j3 = 0; j3 < 3; ++j3) {
      const uint4 u = *(const uint4*)&As[r][seg*24 + j3*8];
      float v[8];
      v[0]=bflo(u.x); v[1]=bfhi(u.x); v[2]=bflo(u.y); v[3]=bfhi(u.y);
      v[4]=bflo(u.z); v[5]=bfhi(u.z); v[6]=bflo(u.w); v[7]=bfhi(u.w);
      #pragma unroll
      for (int j = 0; j < 8; ++j) { s += v[j]; sq += v[j]*v[j]; }
    }
    pSum[tid] = s; pSq[tid] = sq;
  }
  __syncthreads();
  if (tid < 64) {
    const float s  = pSum[tid] + pSum[tid+64] + pSum[tid+128] + pSum[tid+192];
    const float sq = pSq[tid] + pSq[tid+64] + pSq[tid+128] + pSq[tid+192];
    const float mean = s * (1.0f/96.0f);
    mL[tid] = mean;
    sL[tid] = rsqrtf(sq*(1.0f/96.0f) - mean*mean + 1e-5f);
  }
  __syncthreads();
  for (int i = tid; i < 768; i += 256) {
    const int r = i / 12, kk = (i % 12) * 8;
    uint4 u = *(uint4*)&As[r][kk];
    const float m = mL[r], sc = sL[r];
    float v[8];
    v[0]=bflo(u.x); v[1]=bfhi(u.x); v[2]=bflo(u.y); v[3]=bfhi(u.y);
    v[4]=bflo(u.z); v[5]=bfhi(u.z); v[6]=bflo(u.w); v[7]=bfhi(u.w);
    #pragma unroll
    for (int j = 0; j < 8; ++j) v[j] = (v[j] - m)*sc*gL[kk+j] + bL[kk+j];
    *(uint4*)&As[r][kk] = pack8(v);
  }
  __syncthreads();

  short8 af[4][3];
  #pragma unroll
  for (int mt = 0; mt < 4; ++mt)
    #pragma unroll
    for (int kc = 0; kc < 3; ++kc)
      af[mt][kc] = *(const short8*)&As[mt*16 + ml][kc*32 + g8];

  const int rb = 32 * (wave >> 1);
  const int cb = 48 * (wave & 1);
  f32x4 acc2[2][3];
  #pragma unroll
  for (int i = 0; i < 2; ++i)
    #pragma unroll
    for (int nt = 0; nt < 3; ++nt)
      acc2[i][nt] = (f32x4){0.f, 0.f, 0.f, 0.f};

  #pragma unroll
  for (int H = 0; H < 2; ++H) {
    if (H) __syncthreads();

    const int nbg = H*192 + 48*wave;
    const int cl0 = 48*wave;
    short8 bf[3][3];
    #pragma unroll
    for (int nt = 0; nt < 3; ++nt)
      #pragma unroll
      for (int kc = 0; kc < 3; ++kc)
        bf[nt][kc] = *(const short8*)(w1t + (size_t)(nbg + 16*nt + ml)*96 + kc*32 + g8);

    f32x4 acc[4][3];
    #pragma unroll
    for (int mt = 0; mt < 4; ++mt)
      #pragma unroll
      for (int nt = 0; nt < 3; ++nt)
        acc[mt][nt] = (f32x4){0.f, 0.f, 0.f, 0.f};

    #pragma unroll
    for (int kc = 0; kc < 3; ++kc)
      #pragma unroll
      for (int nt = 0; nt < 3; ++nt)
        #pragma unroll
        for (int mt = 0; mt < 4; ++mt)
          acc[mt][nt] = __builtin_amdgcn_mfma_f32_16x16x32_bf16(af[mt][kc], bf[nt][kc], acc[mt][nt], 0, 0, 0);

    #pragma unroll
    for (int nt = 0; nt < 3; ++nt) {
      const float b1v = b1[nbg + 16*nt + ml];
      const int c = cl0 + 16*nt + ml;
      #pragma unroll
      for (int mt = 0; mt < 4; ++mt) {
        #pragma unroll
        for (int r = 0; r < 4; ++r) {
          inter[mt*16 + 4*g + r][c] = f2bfbits(gelu_f(acc[mt][nt][r] + b1v));
        }
      }
    }
    __syncthreads();

    #pragma unroll
    for (int kcl = 0; kcl < 6; ++kcl) {
      const short8 a0 = *(const short8*)&inter[rb + ml][kcl*32 + g8];
      const short8 a1 = *(const short8*)&inter[rb + 16 + ml][kcl*32 + g8];
      #pragma unroll
      for (int nt = 0; nt < 3; ++nt) {
        const short8 b = *(const short8*)(w2t + (size_t)(cb + 16*nt + ml)*384 + H*192 + kcl*32 + g8);
        acc2[0][nt] = __builtin_amdgcn_mfma_f32_16x16x32_bf16(a0, b, acc2[0][nt], 0, 0, 0);
        acc2[1][nt] = __builtin_amdgcn_mfma_f32_16x16x32_bf16(a1, b, acc2[1][nt], 0, 0, 0);
      }
    }
  }

  const unsigned short* xu = (const unsigned short*)xresb;
  #pragma unroll
  for (int i = 0; i < 2; ++i) {
    #pragma unroll
    for (int nt = 0; nt < 3; ++nt) {
      const int col = cb + 16*nt + ml;
      const float b2v = b2[col];
      #pragma unroll
      for (int r = 0; r < 4; ++r) {
        const size_t row = (size_t)(row0 + rb + 16*i + 4*g + r);
        out[row*96 + col] = acc2[i][nt][r] + b2v + bfval(xu[row*96 + col]);
      }
    }
  }
}

// ---------------------------------------------------------------------------
// Launch. ws bytes: qb [0,2E), kb [2E,4E), vb [4E,6E)  (E = L*96 elements),
// MB at [6E, +5.9MB), obb (bf16 attn out) at [+2E), weights at [+165888).
// ---------------------------------------------------------------------------
extern "C" void kernel_launch(void* const* d_in, const int* in_sizes, int n_in,
                              void* d_out, int out_size, void* d_ws, size_t ws_size,
                              hipStream_t stream)
{
  (void)in_sizes; (void)n_in; (void)out_size;
  const float* x    = (const float*)d_in[0];
  const float* n1g  = (const float*)d_in[1];
  const float* n1b  = (const float*)d_in[2];
  const float* qkvw = (const float*)d_in[3];
  const float* qkvb = (const float*)d_in[4];
  const float* rpb  = (const float*)d_in[5];
  const float* pw   = (const float*)d_in[6];
  const float* pb   = (const float*)d_in[7];
  const float* n2g  = (const float*)d_in[8];
  const float* n2b  = (const float*)d_in[9];
  const float* f1w  = (const float*)d_in[10];
  const float* f1b  = (const float*)d_in[11];
  const float* f2w  = (const float*)d_in[12];
  const float* f2b  = (const float*)d_in[13];
  float* out = (float*)d_out;

  const size_t E = (size_t)L_TOK * 96;           // elements
  __hip_bfloat16* qb = (__hip_bfloat16*)d_ws;
  __hip_bfloat16* kb = qb + E;
  __hip_bfloat16* vb = kb + E;
  __hip_bfloat16* xres = (__hip_bfloat16*)d_ws;  // overlays qb (tier-3 path)
  const size_t hs = (size_t)L_TOK * 32;

  unsigned short* qkvwt = (unsigned short*)d_out;       // pre-attn scratch only

  const size_t MB_BYTES = (size_t)8 * 3 * 352 * 352 * 2;    // 5,947,392
  const size_t WT_BYTES = (size_t)(9216 + 36864 + 36864) * 2;  // 165,888
  const size_t off_mb  = (size_t)6 * E;
  const size_t off_obb = off_mb + MB_BYTES;
  const size_t off_wt  = off_obb + (size_t)2 * E;
  const bool mbok  = ws_size >= off_obb;
  const bool fused = ws_size >= off_wt;
  const bool tier1 = ws_size >= off_wt + WT_BYTES;

  unsigned short* MBp = mbok ? (unsigned short*)((char*)d_ws + off_mb) : nullptr;
  __hip_bfloat16* obb = fused ? (__hip_bfloat16*)((char*)d_ws + off_obb) : nullptr;

  if (MBp) k_mb<<<11616, 256, 0, stream>>>(rpb, MBp);

  if (tier1) {
    unsigned short* pwt = (unsigned short*)((char*)d_ws + off_wt);
    unsigned short* w1t = pwt + 9216;
    unsigned short* w2t = w1t + 36864;
    k_tr4<<<432, 256, 0, stream>>>(qkvw, qkvwt, pw, pwt, f1w, w1t, f2w, w2t);
    k_qkv_ln<<<L_TOK/64, 256, 0, stream>>>(x, n1g, n1b, qkvwt, qkvb, hs, qb, kb, vb);
    k_attn_v10<true><<<dim3(256, 3, 2), 256, 0, stream>>>(qb, kb, vb, hs, MBp, (void*)obb);
    k_pm<<<L_TOK/64, 256, 0, stream>>>(obb, pwt, pb, x, n2g, n2b,
                                       w1t, f1b, w2t, f2b, out);
  } else {
    unsigned short* pwt = (unsigned short*)kb;          // dead kb post-attn
    unsigned short* w1t = pwt + 9216;
    unsigned short* w2t = w1t + 36864;
    k_tr<<<108, 256, 0, stream>>>(qkvw, qkvwt, 96, 288);
    k_qkv_ln<<<L_TOK/64, 256, 0, stream>>>(x, n1g, n1b, qkvwt, qkvb, hs, qb, kb, vb);
    if (fused) {
      k_attn_v10<true><<<dim3(256, 3, 2), 256, 0, stream>>>(qb, kb, vb, hs, MBp, (void*)obb);
      k_tr<<<36, 256, 0, stream>>>(pw, pwt, 96, 96);
      k_tr<<<144, 256, 0, stream>>>(f1w, w1t, 96, 384);
      k_tr<<<144, 256, 0, stream>>>(f2w, w2t, 384, 96);
      k_pm<<<L_TOK/64, 256, 0, stream>>>(obb, pwt, pb, x, n2g, n2b,
                                         w1t, f1b, w2t, f2b, out);
    } else {
      float* ob = out;
      k_attn_v10<false><<<dim3(256, 3, 2), 256, 0, stream>>>(qb, kb, vb, hs, MBp, (void*)ob);
      k_tr<<<36, 256, 0, stream>>>(pw, pwt, 96, 96);
      k_tr<<<144, 256, 0, stream>>>(f1w, w1t, 96, 384);
      k_tr<<<144, 256, 0, stream>>>(f2w, w2t, 384, 96);
      k_proj<<<L_TOK/128, 256, 0, stream>>>(ob, pwt, pb, x, xres);
      k_mlp<<<L_TOK/64, 256, 0, stream>>>(xres, n2g, n2b, w1t, f1b, w2t, f2b, out);
    }
  }
}